// Round 2
// baseline (257.423 us; speedup 1.0000x reference)
//
#include <hip/hip_runtime.h>
#include <cstdint>
#include <cstddef>

#define SL 4096
#define DM 768

typedef short s16x8 __attribute__((ext_vector_type(8)));
typedef unsigned short u16x8 __attribute__((ext_vector_type(8)));
typedef unsigned short u16x4 __attribute__((ext_vector_type(4)));
typedef float f32x4 __attribute__((ext_vector_type(4)));

__device__ __forceinline__ unsigned short f2bf(float f) {
  unsigned u = __float_as_uint(f);
  u = u + 0x7fffu + ((u >> 16) & 1u);   // round-to-nearest-even
  return (unsigned short)(u >> 16);
}

// 16B-block XOR swizzle within a 64-short (128B) row (guide G4/T2).
__device__ __forceinline__ int swz(int row, int col) {
  return (row << 6) + ((((col >> 3) ^ row) & 7) << 3) + (col & 7);
}

// async global->LDS, 16B per lane; dest = wave-uniform base + lane*16 (linear),
// source per-lane address carries the swizzle (m173 pattern).
#define ASYNC16(G, L)                                                        \
  __builtin_amdgcn_global_load_lds(                                          \
      (const __attribute__((address_space(1))) void*)(G),                    \
      (__attribute__((address_space(3))) void*)(L), 16, 0, 0)

#define WAITB()                                   \
  do {                                            \
    asm volatile("s_waitcnt vmcnt(0)" ::: "memory"); \
    __builtin_amdgcn_s_barrier();                 \
  } while (0)

extern "C" __global__ __launch_bounds__(256) void k_cvt(
    const float* __restrict__ in, unsigned short* __restrict__ out, int n) {
  int i = (blockIdx.x * 256 + threadIdx.x) * 4;
  if (i >= n) return;
  f32x4 v = *reinterpret_cast<const f32x4*>(in + i);
  u16x4 o;
  o[0] = f2bf(v[0]); o[1] = f2bf(v[1]); o[2] = f2bf(v[2]); o[3] = f2bf(v[3]);
  *reinterpret_cast<u16x4*>(out + i) = o;
}

// fp32 [R][C] -> bf16 [C][R], 64x64 tiles
extern "C" __global__ __launch_bounds__(256) void k_tr(
    const float* __restrict__ in, unsigned short* __restrict__ out, int R, int C) {
  __shared__ float tile[64][65];
  const int t = threadIdx.x;
  const int r0 = blockIdx.y * 64, c0 = blockIdx.x * 64;
  const int lr = t >> 2, lcb = (t & 3) * 16;
  #pragma unroll
  for (int j = 0; j < 16; j += 4) {
    f32x4 v = *reinterpret_cast<const f32x4*>(in + (size_t)(r0 + lr) * C + c0 + lcb + j);
    tile[lr][lcb + j + 0] = v[0];
    tile[lr][lcb + j + 1] = v[1];
    tile[lr][lcb + j + 2] = v[2];
    tile[lr][lcb + j + 3] = v[3];
  }
  __syncthreads();
  #pragma unroll
  for (int j = 0; j < 16; j += 4) {
    u16x4 o;
    o[0] = f2bf(tile[lcb + j + 0][lr]);
    o[1] = f2bf(tile[lcb + j + 1][lr]);
    o[2] = f2bf(tile[lcb + j + 2][lr]);
    o[3] = f2bf(tile[lcb + j + 3][lr]);
    *reinterpret_cast<u16x4*>(out + (size_t)(c0 + lr) * R + r0 + lcb + j) = o;
  }
}

__device__ __forceinline__ void gemm_body(
    const unsigned short* al, const unsigned short* bl, f32x4* acc,
    int wv, int l15, int lg) {
  #pragma unroll
  for (int kc = 0; kc < 2; kc++) {
    s16x8 af = *reinterpret_cast<const s16x8*>(&al[swz(wv * 16 + l15, kc * 32 + lg * 8)]);
    #pragma unroll
    for (int nt = 0; nt < 4; nt++) {
      s16x8 bfr = *reinterpret_cast<const s16x8*>(&bl[swz(nt * 16 + l15, kc * 32 + lg * 8)]);
      acc[nt] = __builtin_amdgcn_mfma_f32_16x16x32_bf16(af, bfr, acc[nt], 0, 0, 0);
    }
  }
}

// QKV GEMM (async dbuf): q pre-scaled by 0.125*log2(e), k row-major, v transposed
extern "C" __global__ __launch_bounds__(256) void k_qkv(
    const unsigned short* __restrict__ xbf, const unsigned short* __restrict__ wt,
    const float* __restrict__ bias, unsigned short* __restrict__ qb,
    unsigned short* __restrict__ kbo, unsigned short* __restrict__ vt) {
  __shared__ alignas(16) unsigned short a_lds[2][4096];
  __shared__ alignas(16) unsigned short b_lds[2][4096];
  const int t = threadIdx.x, wv = t >> 6, l = t & 63;
  const int l15 = l & 15, lg = l >> 4;
  const int m0 = blockIdx.y * 64, n0 = blockIdx.x * 64;
  f32x4 acc[4];
  acc[0] = acc[1] = acc[2] = acc[3] = (f32x4)0.f;
  // pre-swizzled source offsets for the two 1KB chunks this wave stages
  int soff[2];
  #pragma unroll
  for (int c = 0; c < 2; c++) {
    int idx = wv * 128 + c * 64 + l;           // 16B-block index within 8KB tile
    int row = idx >> 3, bp = idx & 7;
    int cb = (bp ^ row) & 7;                   // source col-block under swizzle
    soff[c] = row * DM + cb * 8;               // shorts
  }
  const unsigned short* asrc = xbf + (size_t)m0 * DM;
  const unsigned short* bsrc = wt + (size_t)n0 * DM;
  unsigned short* la = &a_lds[0][0];
  unsigned short* lb = &b_lds[0][0];

#define STAGE_AB(B, KK)                                              \
  do {                                                               \
    ASYNC16(asrc + (KK) + soff[0], la + (B)*4096 + wv * 1024);       \
    ASYNC16(asrc + (KK) + soff[1], la + (B)*4096 + wv * 1024 + 512); \
    ASYNC16(bsrc + (KK) + soff[0], lb + (B)*4096 + wv * 1024);       \
    ASYNC16(bsrc + (KK) + soff[1], lb + (B)*4096 + wv * 1024 + 512); \
  } while (0)

  STAGE_AB(0, 0);
  WAITB();
  for (int kk = 0; kk < DM; kk += 128) {
    STAGE_AB(1, kk + 64);
    gemm_body(&a_lds[0][0], &b_lds[0][0], acc, wv, l15, lg);
    WAITB();
    if (kk + 128 < DM) STAGE_AB(0, kk + 128);
    gemm_body(&a_lds[1][0], &b_lds[1][0], acc, wv, l15, lg);
    WAITB();
  }
#undef STAGE_AB
  const int mb = m0 + wv * 16 + lg * 4;
  #pragma unroll
  for (int nt = 0; nt < 4; nt++) {
    const int n = n0 + nt * 16 + l15;
    const float bv = bias[n];
    const int sec = n / DM;             // 0=q 1=k 2=v (uniform per tile)
    const int nn = n - sec * DM;
    const int h = nn >> 6, d = nn & 63;
    if (sec == 0) {
      #pragma unroll
      for (int r = 0; r < 4; r++)
        qb[((size_t)h * SL + mb + r) * 64 + d] = f2bf((acc[nt][r] + bv) * 0.180336880f);
    } else if (sec == 1) {
      #pragma unroll
      for (int r = 0; r < 4; r++)
        kbo[((size_t)h * SL + mb + r) * 64 + d] = f2bf(acc[nt][r] + bv);
    } else {
      u16x4 o;
      #pragma unroll
      for (int r = 0; r < 4; r++) o[r] = f2bf(acc[nt][r] + bv);
      *reinterpret_cast<u16x4*>(vt + ((size_t)h * 64 + d) * SL + mb) = o;
    }
  }
}

__device__ __forceinline__ void attn_body(
    const unsigned short* kb, const unsigned short* vb, unsigned short* pw,
    const s16x8* qf, f32x4* po, float* mrun, float* lrun, int l15, int lg) {
  // S' = (Q*log2e/8) K^T : 16x64 per wave (scores already in log2 domain)
  f32x4 s[4];
  #pragma unroll
  for (int nt = 0; nt < 4; nt++) {
    s[nt] = (f32x4)0.f;
    #pragma unroll
    for (int kc = 0; kc < 2; kc++) {
      s16x8 kf = *reinterpret_cast<const s16x8*>(&kb[swz(nt * 16 + l15, kc * 32 + lg * 8)]);
      s[nt] = __builtin_amdgcn_mfma_f32_16x16x32_bf16(qf[kc], kf, s[nt], 0, 0, 0);
    }
  }
  float tm[4], psum[4], corr[4];
  #pragma unroll
  for (int r = 0; r < 4; r++)
    tm[r] = fmaxf(fmaxf(s[0][r], s[1][r]), fmaxf(s[2][r], s[3][r]));
  #pragma unroll
  for (int off = 1; off < 16; off <<= 1) {
    #pragma unroll
    for (int r = 0; r < 4; r++) tm[r] = fmaxf(tm[r], __shfl_xor(tm[r], off, 64));
  }
  #pragma unroll
  for (int r = 0; r < 4; r++) {
    float mn = fmaxf(mrun[r], tm[r]);
    corr[r] = exp2f(mrun[r] - mn);
    mrun[r] = mn;
    psum[r] = 0.f;
  }
  #pragma unroll
  for (int nt = 0; nt < 4; nt++) {
    #pragma unroll
    for (int r = 0; r < 4; r++) {
      float p = exp2f(s[nt][r] - mrun[r]);
      s[nt][r] = p;
      psum[r] += p;
    }
  }
  #pragma unroll
  for (int off = 1; off < 16; off <<= 1) {
    #pragma unroll
    for (int r = 0; r < 4; r++) psum[r] += __shfl_xor(psum[r], off, 64);
  }
  #pragma unroll
  for (int r = 0; r < 4; r++) lrun[r] = lrun[r] * corr[r] + psum[r];
  #pragma unroll
  for (int nt = 0; nt < 4; nt++) {
    #pragma unroll
    for (int r = 0; r < 4; r++) po[nt][r] *= corr[r];
  }
  // transpose P through wave-private LDS (C-layout -> A-layout); same-wave dep,
  // compiler inserts the lgkmcnt waits.
  #pragma unroll
  for (int nt = 0; nt < 4; nt++) {
    #pragma unroll
    for (int r = 0; r < 4; r++)
      pw[swz(lg * 4 + r, nt * 16 + l15)] = f2bf(s[nt][r]);
  }
  // O += P V  (V^T staged so B-frags are contiguous)
  #pragma unroll
  for (int kc = 0; kc < 2; kc++) {
    s16x8 pf = *reinterpret_cast<const s16x8*>(&pw[swz(l15, kc * 32 + lg * 8)]);
    #pragma unroll
    for (int nt = 0; nt < 4; nt++) {
      s16x8 vf = *reinterpret_cast<const s16x8*>(&vb[swz(nt * 16 + l15, kc * 32 + lg * 8)]);
      po[nt] = __builtin_amdgcn_mfma_f32_16x16x32_bf16(pf, vf, po[nt], 0, 0, 0);
    }
  }
}

// Flash attention, async double-buffered K/V staging, one barrier per KV block
extern "C" __global__ __launch_bounds__(256) void k_attn(
    const unsigned short* __restrict__ qb, const unsigned short* __restrict__ kbi,
    const unsigned short* __restrict__ vt, unsigned short* __restrict__ aout) {
  __shared__ alignas(16) unsigned short k_lds[2][4096];
  __shared__ alignas(16) unsigned short v_lds[2][4096];
  __shared__ alignas(16) unsigned short p_lds[4096];   // 4 waves x [16][64]
  const int t = threadIdx.x, wv = t >> 6, l = t & 63;
  const int l15 = l & 15, lg = l >> 4;
  const int h = blockIdx.y;
  const int q0 = blockIdx.x * 64;
  const unsigned short* qh = qb + (size_t)h * SL * 64;
  const unsigned short* kh = kbi + (size_t)h * SL * 64;
  const unsigned short* vh = vt + (size_t)h * 64 * SL;
  s16x8 qf[2];
  {
    const size_t qoff = (size_t)(q0 + wv * 16 + l15) * 64 + lg * 8;
    qf[0] = *reinterpret_cast<const s16x8*>(qh + qoff);
    qf[1] = *reinterpret_cast<const s16x8*>(qh + qoff + 32);
  }
  f32x4 po[4];
  po[0] = po[1] = po[2] = po[3] = (f32x4)0.f;
  float mrun[4] = {-1e30f, -1e30f, -1e30f, -1e30f};
  float lrun[4] = {0.f, 0.f, 0.f, 0.f};
  unsigned short* pw = p_lds + wv * 1024;
  // pre-swizzled source offsets (K rows are seq, V rows are d)
  int koff[2], voff[2];
  #pragma unroll
  for (int c = 0; c < 2; c++) {
    int idx = wv * 128 + c * 64 + l;
    int row = idx >> 3, bp = idx & 7;
    int cb = (bp ^ row) & 7;
    koff[c] = row * 64 + cb * 8;     // within K tile: (row)*64 + cb*8 shorts
    voff[c] = row * SL + cb * 8;     // within V^T:    (d)*4096 + cb*8 shorts
  }
  unsigned short* lk = &k_lds[0][0];
  unsigned short* lv = &v_lds[0][0];

#define STAGE_KV(B, KB0)                                                  \
  do {                                                                    \
    ASYNC16(kh + (size_t)(KB0) * 64 + koff[0], lk + (B)*4096 + wv * 1024);       \
    ASYNC16(kh + (size_t)(KB0) * 64 + koff[1], lk + (B)*4096 + wv * 1024 + 512); \
    ASYNC16(vh + (KB0) + voff[0], lv + (B)*4096 + wv * 1024);             \
    ASYNC16(vh + (KB0) + voff[1], lv + (B)*4096 + wv * 1024 + 512);       \
  } while (0)

  STAGE_KV(0, 0);
  WAITB();
  for (int kb0 = 0; kb0 < SL; kb0 += 128) {
    STAGE_KV(1, kb0 + 64);
    attn_body(&k_lds[0][0], &v_lds[0][0], pw, qf, po, mrun, lrun, l15, lg);
    WAITB();
    if (kb0 + 128 < SL) STAGE_KV(0, kb0 + 128);
    attn_body(&k_lds[1][0], &v_lds[1][0], pw, qf, po, mrun, lrun, l15, lg);
    WAITB();
  }
#undef STAGE_KV
  const int m = q0 + wv * 16 + lg * 4;
  #pragma unroll
  for (int nt = 0; nt < 4; nt++) {
    const int col = h * 64 + nt * 16 + l15;
    #pragma unroll
    for (int r = 0; r < 4; r++)
      aout[(size_t)(m + r) * DM + col] = f2bf(po[nt][r] / lrun[r]);
  }
}

// out-proj GEMM + bias + residual -> y (fp32), async dbuf
extern "C" __global__ __launch_bounds__(256) void k_out(
    const unsigned short* __restrict__ abf, const unsigned short* __restrict__ wot,
    const float* __restrict__ bias, const float* __restrict__ x, float* __restrict__ y) {
  __shared__ alignas(16) unsigned short a_lds[2][4096];
  __shared__ alignas(16) unsigned short b_lds[2][4096];
  const int t = threadIdx.x, wv = t >> 6, l = t & 63;
  const int l15 = l & 15, lg = l >> 4;
  const int m0 = blockIdx.y * 64, n0 = blockIdx.x * 64;
  f32x4 acc[4];
  acc[0] = acc[1] = acc[2] = acc[3] = (f32x4)0.f;
  int soff[2];
  #pragma unroll
  for (int c = 0; c < 2; c++) {
    int idx = wv * 128 + c * 64 + l;
    int row = idx >> 3, bp = idx & 7;
    int cb = (bp ^ row) & 7;
    soff[c] = row * DM + cb * 8;
  }
  const unsigned short* asrc = abf + (size_t)m0 * DM;
  const unsigned short* bsrc = wot + (size_t)n0 * DM;
  unsigned short* la = &a_lds[0][0];
  unsigned short* lb = &b_lds[0][0];

#define STAGE_AB(B, KK)                                              \
  do {                                                               \
    ASYNC16(asrc + (KK) + soff[0], la + (B)*4096 + wv * 1024);       \
    ASYNC16(asrc + (KK) + soff[1], la + (B)*4096 + wv * 1024 + 512); \
    ASYNC16(bsrc + (KK) + soff[0], lb + (B)*4096 + wv * 1024);       \
    ASYNC16(bsrc + (KK) + soff[1], lb + (B)*4096 + wv * 1024 + 512); \
  } while (0)

  STAGE_AB(0, 0);
  WAITB();
  for (int kk = 0; kk < DM; kk += 128) {
    STAGE_AB(1, kk + 64);
    gemm_body(&a_lds[0][0], &b_lds[0][0], acc, wv, l15, lg);
    WAITB();
    if (kk + 128 < DM) STAGE_AB(0, kk + 128);
    gemm_body(&a_lds[1][0], &b_lds[1][0], acc, wv, l15, lg);
    WAITB();
  }
#undef STAGE_AB
  const int mb = m0 + wv * 16 + lg * 4;
  #pragma unroll
  for (int nt = 0; nt < 4; nt++) {
    const int n = n0 + nt * 16 + l15;
    const float bv = bias[n];
    #pragma unroll
    for (int r = 0; r < 4; r++)
      y[(size_t)(mb + r) * DM + n] = acc[nt][r] + bv + x[(size_t)(mb + r) * DM + n];
  }
}

extern "C" __global__ __launch_bounds__(256) void k_ln(
    const float* __restrict__ y, const float* __restrict__ g, const float* __restrict__ b,
    float* __restrict__ out) {
  const int row = blockIdx.x, t = threadIdx.x;
  const float* yr = y + (size_t)row * DM;
  float v0 = yr[t], v1 = yr[t + 256], v2 = yr[t + 512];
  float sum = v0 + v1 + v2;
  float sq = v0 * v0 + v1 * v1 + v2 * v2;
  #pragma unroll
  for (int off = 1; off < 64; off <<= 1) {
    sum += __shfl_xor(sum, off, 64);
    sq += __shfl_xor(sq, off, 64);
  }
  __shared__ float ls[8];
  const int wv = t >> 6, l = t & 63;
  if (l == 0) { ls[wv] = sum; ls[4 + wv] = sq; }
  __syncthreads();
  sum = ls[0] + ls[1] + ls[2] + ls[3];
  sq = ls[4] + ls[5] + ls[6] + ls[7];
  const float mu = sum * (1.f / DM);
  const float rstd = rsqrtf(sq * (1.f / DM) - mu * mu + 1e-5f);
  out[(size_t)row * DM + t] = (v0 - mu) * rstd * g[t] + b[t];
  out[(size_t)row * DM + t + 256] = (v1 - mu) * rstd * g[t + 256] + b[t + 256];
  out[(size_t)row * DM + t + 512] = (v2 - mu) * rstd * g[t + 512] + b[t + 512];
}

extern "C" void kernel_launch(void* const* d_in, const int* in_sizes, int n_in,
                              void* d_out, int out_size, void* d_ws, size_t ws_size,
                              hipStream_t stream) {
  (void)in_sizes; (void)n_in; (void)out_size; (void)ws_size;
  const float* x = (const float*)d_in[0];
  const float* Wa = (const float*)d_in[1];
  const float* ba = (const float*)d_in[2];
  const float* Wo = (const float*)d_in[3];
  const float* bo = (const float*)d_in[4];
  const float* lng = (const float*)d_in[5];
  const float* lnb = (const float*)d_in[6];
  float* out = (float*)d_out;

  unsigned short* ws16 = (unsigned short*)d_ws;
  unsigned short* xbf = ws16;                 // 4096x768
  unsigned short* wat = xbf + 3145728;        // 2304x768 (W_attn^T)
  unsigned short* wot = wat + 1769472;        // 768x768  (W_out^T)
  unsigned short* qbf = wot + 589824;         // [12][4096][64]
  unsigned short* kbf = qbf + 3145728;        // [12][4096][64]
  unsigned short* vtb = kbf + 3145728;        // [12][64][4096]
  unsigned short* aob = vtb + 3145728;        // 4096x768 attn out
  float* ybuf = (float*)(aob + 3145728);      // 4096x768 fp32

  k_cvt<<<3072, 256, 0, stream>>>(x, xbf, 3145728);
  k_tr<<<dim3(36, 12), 256, 0, stream>>>(Wa, wat, 768, 2304);
  k_tr<<<dim3(12, 12), 256, 0, stream>>>(Wo, wot, 768, 768);
  k_qkv<<<dim3(36, 64), 256, 0, stream>>>(xbf, wat, ba, qbf, kbf, vtb);
  k_attn<<<dim3(64, 12), 256, 0, stream>>>(qbf, kbf, vtb, aob);
  k_out<<<dim3(12, 64), 256, 0, stream>>>(aob, wot, bo, x, ybuf);
  k_ln<<<4096, 256, 0, stream>>>(ybuf, lng, lnb, out);
}

// Round 3
// 207.592 us; speedup vs baseline: 1.2400x; 1.2400x over previous
//
#include <hip/hip_runtime.h>
#include <cstdint>
#include <cstddef>

#define SL 4096
#define DM 768

typedef short s16x8 __attribute__((ext_vector_type(8)));
typedef unsigned short u16x8 __attribute__((ext_vector_type(8)));
typedef unsigned short u16x4 __attribute__((ext_vector_type(4)));
typedef float f32x4 __attribute__((ext_vector_type(4)));
typedef unsigned int u32x4 __attribute__((ext_vector_type(4)));

__device__ __forceinline__ unsigned short f2bf(float f) {
  unsigned u = __float_as_uint(f);
  u = u + 0x7fffu + ((u >> 16) & 1u);   // round-to-nearest-even
  return (unsigned short)(u >> 16);
}

// 16B-block XOR swizzle within a 64-short (128B) row (guide G4/T2).
__device__ __forceinline__ int swz(int row, int col) {
  return (row << 6) + ((((col >> 3) ^ row) & 7) << 3) + (col & 7);
}

// async global->LDS, 16B per lane; dest = wave-uniform base + lane*16 (linear),
// source per-lane address carries the swizzle (m173 pattern).
#define ASYNC16(G, L)                                                        \
  __builtin_amdgcn_global_load_lds(                                          \
      (const __attribute__((address_space(1))) void*)(G),                    \
      (__attribute__((address_space(3))) void*)(L), 16, 0, 0)

#define WAITB()                                   \
  do {                                            \
    asm volatile("s_waitcnt vmcnt(0)" ::: "memory"); \
    __builtin_amdgcn_s_barrier();                 \
  } while (0)

extern "C" __global__ __launch_bounds__(256) void k_cvt(
    const float* __restrict__ in, unsigned short* __restrict__ out, int n) {
  int i = (blockIdx.x * 256 + threadIdx.x) * 4;
  if (i >= n) return;
  f32x4 v = *reinterpret_cast<const f32x4*>(in + i);
  u16x4 o;
  o[0] = f2bf(v[0]); o[1] = f2bf(v[1]); o[2] = f2bf(v[2]); o[3] = f2bf(v[3]);
  *reinterpret_cast<u16x4*>(out + i) = o;
}

// fp32 [R][C] -> bf16 [C][R], 64x64 tiles
extern "C" __global__ __launch_bounds__(256) void k_tr(
    const float* __restrict__ in, unsigned short* __restrict__ out, int R, int C) {
  __shared__ float tile[64][65];
  const int t = threadIdx.x;
  const int r0 = blockIdx.y * 64, c0 = blockIdx.x * 64;
  const int lr = t >> 2, lcb = (t & 3) * 16;
  #pragma unroll
  for (int j = 0; j < 16; j += 4) {
    f32x4 v = *reinterpret_cast<const f32x4*>(in + (size_t)(r0 + lr) * C + c0 + lcb + j);
    tile[lr][lcb + j + 0] = v[0];
    tile[lr][lcb + j + 1] = v[1];
    tile[lr][lcb + j + 2] = v[2];
    tile[lr][lcb + j + 3] = v[3];
  }
  __syncthreads();
  #pragma unroll
  for (int j = 0; j < 16; j += 4) {
    u16x4 o;
    o[0] = f2bf(tile[lcb + j + 0][lr]);
    o[1] = f2bf(tile[lcb + j + 1][lr]);
    o[2] = f2bf(tile[lcb + j + 2][lr]);
    o[3] = f2bf(tile[lcb + j + 3][lr]);
    *reinterpret_cast<u16x4*>(out + (size_t)(c0 + lr) * R + r0 + lcb + j) = o;
  }
}

__device__ __forceinline__ void gemm_body(
    const unsigned short* al, const unsigned short* bl, f32x4* acc,
    int wv, int l15, int lg) {
  #pragma unroll
  for (int kc = 0; kc < 2; kc++) {
    s16x8 af = *reinterpret_cast<const s16x8*>(&al[swz(wv * 16 + l15, kc * 32 + lg * 8)]);
    #pragma unroll
    for (int nt = 0; nt < 4; nt++) {
      s16x8 bfr = *reinterpret_cast<const s16x8*>(&bl[swz(nt * 16 + l15, kc * 32 + lg * 8)]);
      acc[nt] = __builtin_amdgcn_mfma_f32_16x16x32_bf16(af, bfr, acc[nt], 0, 0, 0);
    }
  }
}

// QKV GEMM (async dbuf): q pre-scaled by 0.125*log2(e), k row-major, v transposed
extern "C" __global__ __launch_bounds__(256) void k_qkv(
    const unsigned short* __restrict__ xbf, const unsigned short* __restrict__ wt,
    const float* __restrict__ bias, unsigned short* __restrict__ qb,
    unsigned short* __restrict__ kbo, unsigned short* __restrict__ vt) {
  __shared__ alignas(16) unsigned short a_lds[2][4096];
  __shared__ alignas(16) unsigned short b_lds[2][4096];
  const int t = threadIdx.x, wv = t >> 6, l = t & 63;
  const int l15 = l & 15, lg = l >> 4;
  const int m0 = blockIdx.y * 64, n0 = blockIdx.x * 64;
  f32x4 acc[4];
  acc[0] = acc[1] = acc[2] = acc[3] = (f32x4)0.f;
  // pre-swizzled source offsets for the two 1KB chunks this wave stages
  int soff[2];
  #pragma unroll
  for (int c = 0; c < 2; c++) {
    int idx = wv * 128 + c * 64 + l;           // 16B-block index within 8KB tile
    int row = idx >> 3, bp = idx & 7;
    int cb = (bp ^ row) & 7;                   // source col-block under swizzle
    soff[c] = row * DM + cb * 8;               // shorts
  }
  const unsigned short* asrc = xbf + (size_t)m0 * DM;
  const unsigned short* bsrc = wt + (size_t)n0 * DM;
  unsigned short* la = &a_lds[0][0];
  unsigned short* lb = &b_lds[0][0];

#define STAGE_AB(B, KK)                                              \
  do {                                                               \
    ASYNC16(asrc + (KK) + soff[0], la + (B)*4096 + wv * 1024);       \
    ASYNC16(asrc + (KK) + soff[1], la + (B)*4096 + wv * 1024 + 512); \
    ASYNC16(bsrc + (KK) + soff[0], lb + (B)*4096 + wv * 1024);       \
    ASYNC16(bsrc + (KK) + soff[1], lb + (B)*4096 + wv * 1024 + 512); \
  } while (0)

  STAGE_AB(0, 0);
  WAITB();
  for (int kk = 0; kk < DM; kk += 128) {
    STAGE_AB(1, kk + 64);
    gemm_body(&a_lds[0][0], &b_lds[0][0], acc, wv, l15, lg);
    WAITB();
    if (kk + 128 < DM) STAGE_AB(0, kk + 128);
    gemm_body(&a_lds[1][0], &b_lds[1][0], acc, wv, l15, lg);
    WAITB();
  }
#undef STAGE_AB
  const int mb = m0 + wv * 16 + lg * 4;
  #pragma unroll
  for (int nt = 0; nt < 4; nt++) {
    const int n = n0 + nt * 16 + l15;
    const float bv = bias[n];
    const int sec = n / DM;             // 0=q 1=k 2=v (uniform per tile)
    const int nn = n - sec * DM;
    const int h = nn >> 6, d = nn & 63;
    if (sec == 0) {
      #pragma unroll
      for (int r = 0; r < 4; r++)
        qb[((size_t)h * SL + mb + r) * 64 + d] = f2bf((acc[nt][r] + bv) * 0.180336880f);
    } else if (sec == 1) {
      #pragma unroll
      for (int r = 0; r < 4; r++)
        kbo[((size_t)h * SL + mb + r) * 64 + d] = f2bf(acc[nt][r] + bv);
    } else {
      u16x4 o;
      #pragma unroll
      for (int r = 0; r < 4; r++) o[r] = f2bf(acc[nt][r] + bv);
      *reinterpret_cast<u16x4*>(vt + ((size_t)h * 64 + d) * SL + mb) = o;
    }
  }
}

// Swapped attention body: S^T = mfma(K,Q) so each lane owns ONE q-row's scores;
// softmax is in-lane + 2 shfl; P^T B-frags built via cvt_pk + 16 bpermute;
// PV swapped (O^T = mfma(V^T, P^T)) so m/l/corr stay lane-local.
__device__ __forceinline__ void attn_body(
    const unsigned short* kb, const unsigned short* vb,
    const s16x8* qf, f32x4* po, float& mrun, float& lrun,
    int l15, int lg, int sl0, int sl1, bool ghi) {
  f32x4 s[4];
  s[0] = s[1] = s[2] = s[3] = (f32x4)0.f;
  __builtin_amdgcn_s_setprio(1);
  #pragma unroll
  for (int kc = 0; kc < 2; kc++) {
    #pragma unroll
    for (int nt = 0; nt < 4; nt++) {
      s16x8 kf = *reinterpret_cast<const s16x8*>(&kb[swz(nt * 16 + l15, kc * 32 + lg * 8)]);
      s[nt] = __builtin_amdgcn_mfma_f32_16x16x32_bf16(kf, qf[kc], s[nt], 0, 0, 0);
    }
  }
  __builtin_amdgcn_s_setprio(0);
  // scores are in log2 domain (Q pre-scaled by 0.125*log2e)
  float tm = s[0][0];
  #pragma unroll
  for (int nt = 0; nt < 4; nt++)
    #pragma unroll
    for (int r = 0; r < 4; r++) tm = fmaxf(tm, s[nt][r]);
  tm = fmaxf(tm, __shfl_xor(tm, 16, 64));
  tm = fmaxf(tm, __shfl_xor(tm, 32, 64));
  const float mn = fmaxf(mrun, tm);
  const float corr = exp2f(mrun - mn);
  mrun = mn;
  float psum = 0.f;
  #pragma unroll
  for (int nt = 0; nt < 4; nt++) {
    #pragma unroll
    for (int r = 0; r < 4; r++) {
      float p = exp2f(s[nt][r] - mn);
      s[nt][r] = p;
      psum += p;
    }
  }
  // pack P rows to bf16 pairs: pk[nt][w] = (P[4nt+2w], P[4nt+2w+1]) for this q
  unsigned pk[4][2];
  #pragma unroll
  for (int nt = 0; nt < 4; nt++) {
    asm("v_cvt_pk_bf16_f32 %0, %1, %2" : "=v"(pk[nt][0]) : "v"(s[nt][0]), "v"(s[nt][1]));
    asm("v_cvt_pk_bf16_f32 %0, %1, %2" : "=v"(pk[nt][1]) : "v"(s[nt][2]), "v"(s[nt][3]));
  }
  psum += __shfl_xor(psum, 16, 64);
  psum += __shfl_xor(psum, 32, 64);
  lrun = lrun * corr + psum;
  #pragma unroll
  for (int nt = 0; nt < 4; nt++) {
    #pragma unroll
    for (int r = 0; r < 4; r++) po[nt][r] *= corr;
  }
  // exchange within each q-column (lanes l15+{0,16,32,48}) to build P^T B-frags
  __builtin_amdgcn_s_setprio(1);
  #pragma unroll
  for (int kc = 0; kc < 2; kc++) {
    unsigned a0 = (unsigned)__shfl((int)pk[kc * 2][0], sl0, 64);
    unsigned a1 = (unsigned)__shfl((int)pk[kc * 2][1], sl0, 64);
    unsigned a2 = (unsigned)__shfl((int)pk[kc * 2 + 1][0], sl0, 64);
    unsigned a3 = (unsigned)__shfl((int)pk[kc * 2 + 1][1], sl0, 64);
    unsigned b0 = (unsigned)__shfl((int)pk[kc * 2][0], sl1, 64);
    unsigned b1 = (unsigned)__shfl((int)pk[kc * 2][1], sl1, 64);
    unsigned b2 = (unsigned)__shfl((int)pk[kc * 2 + 1][0], sl1, 64);
    unsigned b3 = (unsigned)__shfl((int)pk[kc * 2 + 1][1], sl1, 64);
    u32x4 w;
    w[0] = ghi ? a2 : a0;
    w[1] = ghi ? a3 : a1;
    w[2] = ghi ? b2 : b0;
    w[3] = ghi ? b3 : b1;
    s16x8 pbf = *reinterpret_cast<s16x8*>(&w);
    #pragma unroll
    for (int nt = 0; nt < 4; nt++) {
      s16x8 vf = *reinterpret_cast<const s16x8*>(&vb[swz(nt * 16 + l15, kc * 32 + lg * 8)]);
      po[nt] = __builtin_amdgcn_mfma_f32_16x16x32_bf16(vf, pbf, po[nt], 0, 0, 0);
    }
  }
  __builtin_amdgcn_s_setprio(0);
}

// Flash attention, async double-buffered K/V staging, swapped-MFMA softmax
extern "C" __global__ __launch_bounds__(256) void k_attn(
    const unsigned short* __restrict__ qb, const unsigned short* __restrict__ kbi,
    const unsigned short* __restrict__ vt, unsigned short* __restrict__ aout) {
  __shared__ alignas(16) unsigned short k_lds[2][4096];
  __shared__ alignas(16) unsigned short v_lds[2][4096];
  const int t = threadIdx.x, wv = t >> 6, l = t & 63;
  const int l15 = l & 15, lg = l >> 4;
  const int h = blockIdx.y;
  const int q0 = blockIdx.x * 64;
  const unsigned short* qh = qb + (size_t)h * SL * 64;
  const unsigned short* kh = kbi + (size_t)h * SL * 64;
  const unsigned short* vh = vt + (size_t)h * 64 * SL;
  s16x8 qf[2];
  {
    const size_t qoff = (size_t)(q0 + wv * 16 + l15) * 64 + lg * 8;
    qf[0] = *reinterpret_cast<const s16x8*>(qh + qoff);
    qf[1] = *reinterpret_cast<const s16x8*>(qh + qoff + 32);
  }
  f32x4 po[4];
  po[0] = po[1] = po[2] = po[3] = (f32x4)0.f;
  float mrun = -1e30f, lrun = 0.f;
  const bool ghi = (lg & 2) != 0;                 // selects nt = 2kc+1 sources
  const int sl0 = l15 + ((lg & 1) ? 32 : 0);      // source lane for j=0..3
  const int sl1 = sl0 + 16;                       // source lane for j=4..7
  // pre-swizzled source offsets (K rows are seq, V rows are d)
  int koff[2], voff[2];
  #pragma unroll
  for (int c = 0; c < 2; c++) {
    int idx = wv * 128 + c * 64 + l;
    int row = idx >> 3, bp = idx & 7;
    int cb = (bp ^ row) & 7;
    koff[c] = row * 64 + cb * 8;     // within K tile: (row)*64 + cb*8 shorts
    voff[c] = row * SL + cb * 8;     // within V^T:    (d)*4096 + cb*8 shorts
  }
  unsigned short* lk = &k_lds[0][0];
  unsigned short* lv = &v_lds[0][0];

#define STAGE_KV(B, KB0)                                                  \
  do {                                                                    \
    ASYNC16(kh + (size_t)(KB0) * 64 + koff[0], lk + (B)*4096 + wv * 1024);       \
    ASYNC16(kh + (size_t)(KB0) * 64 + koff[1], lk + (B)*4096 + wv * 1024 + 512); \
    ASYNC16(vh + (KB0) + voff[0], lv + (B)*4096 + wv * 1024);             \
    ASYNC16(vh + (KB0) + voff[1], lv + (B)*4096 + wv * 1024 + 512);       \
  } while (0)

  STAGE_KV(0, 0);
  WAITB();
  for (int kb0 = 0; kb0 < SL; kb0 += 128) {
    STAGE_KV(1, kb0 + 64);
    attn_body(&k_lds[0][0], &v_lds[0][0], qf, po, mrun, lrun, l15, lg, sl0, sl1, ghi);
    WAITB();
    if (kb0 + 128 < SL) STAGE_KV(0, kb0 + 128);
    attn_body(&k_lds[1][0], &v_lds[1][0], qf, po, mrun, lrun, l15, lg, sl0, sl1, ghi);
    WAITB();
  }
#undef STAGE_KV
  // lane-local epilogue: O^T[d][q], q = l15 lane-local, d = nt*16+lg*4+r
  const float inv = 1.f / lrun;
  const int q = q0 + wv * 16 + l15;
  #pragma unroll
  for (int nt = 0; nt < 4; nt++) {
    u16x4 o;
    #pragma unroll
    for (int r = 0; r < 4; r++) o[r] = f2bf(po[nt][r] * inv);
    *reinterpret_cast<u16x4*>(aout + (size_t)q * DM + h * 64 + nt * 16 + lg * 4) = o;
  }
}

// out-proj GEMM + bias + residual -> y (fp32), async dbuf
extern "C" __global__ __launch_bounds__(256) void k_out(
    const unsigned short* __restrict__ abf, const unsigned short* __restrict__ wot,
    const float* __restrict__ bias, const float* __restrict__ x, float* __restrict__ y) {
  __shared__ alignas(16) unsigned short a_lds[2][4096];
  __shared__ alignas(16) unsigned short b_lds[2][4096];
  const int t = threadIdx.x, wv = t >> 6, l = t & 63;
  const int l15 = l & 15, lg = l >> 4;
  const int m0 = blockIdx.y * 64, n0 = blockIdx.x * 64;
  f32x4 acc[4];
  acc[0] = acc[1] = acc[2] = acc[3] = (f32x4)0.f;
  int soff[2];
  #pragma unroll
  for (int c = 0; c < 2; c++) {
    int idx = wv * 128 + c * 64 + l;
    int row = idx >> 3, bp = idx & 7;
    int cb = (bp ^ row) & 7;
    soff[c] = row * DM + cb * 8;
  }
  const unsigned short* asrc = abf + (size_t)m0 * DM;
  const unsigned short* bsrc = wot + (size_t)n0 * DM;
  unsigned short* la = &a_lds[0][0];
  unsigned short* lb = &b_lds[0][0];

#define STAGE_AB(B, KK)                                              \
  do {                                                               \
    ASYNC16(asrc + (KK) + soff[0], la + (B)*4096 + wv * 1024);       \
    ASYNC16(asrc + (KK) + soff[1], la + (B)*4096 + wv * 1024 + 512); \
    ASYNC16(bsrc + (KK) + soff[0], lb + (B)*4096 + wv * 1024);       \
    ASYNC16(bsrc + (KK) + soff[1], lb + (B)*4096 + wv * 1024 + 512); \
  } while (0)

  STAGE_AB(0, 0);
  WAITB();
  for (int kk = 0; kk < DM; kk += 128) {
    STAGE_AB(1, kk + 64);
    gemm_body(&a_lds[0][0], &b_lds[0][0], acc, wv, l15, lg);
    WAITB();
    if (kk + 128 < DM) STAGE_AB(0, kk + 128);
    gemm_body(&a_lds[1][0], &b_lds[1][0], acc, wv, l15, lg);
    WAITB();
  }
#undef STAGE_AB
  const int mb = m0 + wv * 16 + lg * 4;
  #pragma unroll
  for (int nt = 0; nt < 4; nt++) {
    const int n = n0 + nt * 16 + l15;
    const float bv = bias[n];
    #pragma unroll
    for (int r = 0; r < 4; r++)
      y[(size_t)(mb + r) * DM + n] = acc[nt][r] + bv + x[(size_t)(mb + r) * DM + n];
  }
}

extern "C" __global__ __launch_bounds__(256) void k_ln(
    const float* __restrict__ y, const float* __restrict__ g, const float* __restrict__ b,
    float* __restrict__ out) {
  const int row = blockIdx.x, t = threadIdx.x;
  const float* yr = y + (size_t)row * DM;
  float v0 = yr[t], v1 = yr[t + 256], v2 = yr[t + 512];
  float sum = v0 + v1 + v2;
  float sq = v0 * v0 + v1 * v1 + v2 * v2;
  #pragma unroll
  for (int off = 1; off < 64; off <<= 1) {
    sum += __shfl_xor(sum, off, 64);
    sq += __shfl_xor(sq, off, 64);
  }
  __shared__ float ls[8];
  const int wv = t >> 6, l = t & 63;
  if (l == 0) { ls[wv] = sum; ls[4 + wv] = sq; }
  __syncthreads();
  sum = ls[0] + ls[1] + ls[2] + ls[3];
  sq = ls[4] + ls[5] + ls[6] + ls[7];
  const float mu = sum * (1.f / DM);
  const float rstd = rsqrtf(sq * (1.f / DM) - mu * mu + 1e-5f);
  out[(size_t)row * DM + t] = (v0 - mu) * rstd * g[t] + b[t];
  out[(size_t)row * DM + t + 256] = (v1 - mu) * rstd * g[t + 256] + b[t + 256];
  out[(size_t)row * DM + t + 512] = (v2 - mu) * rstd * g[t + 512] + b[t + 512];
}

extern "C" void kernel_launch(void* const* d_in, const int* in_sizes, int n_in,
                              void* d_out, int out_size, void* d_ws, size_t ws_size,
                              hipStream_t stream) {
  (void)in_sizes; (void)n_in; (void)out_size; (void)ws_size;
  const float* x = (const float*)d_in[0];
  const float* Wa = (const float*)d_in[1];
  const float* ba = (const float*)d_in[2];
  const float* Wo = (const float*)d_in[3];
  const float* bo = (const float*)d_in[4];
  const float* lng = (const float*)d_in[5];
  const float* lnb = (const float*)d_in[6];
  float* out = (float*)d_out;

  unsigned short* ws16 = (unsigned short*)d_ws;
  unsigned short* xbf = ws16;                 // 4096x768
  unsigned short* wat = xbf + 3145728;        // 2304x768 (W_attn^T)
  unsigned short* wot = wat + 1769472;        // 768x768  (W_out^T)
  unsigned short* qbf = wot + 589824;         // [12][4096][64]
  unsigned short* kbf = qbf + 3145728;        // [12][4096][64]
  unsigned short* vtb = kbf + 3145728;        // [12][64][4096]
  unsigned short* aob = vtb + 3145728;        // 4096x768 attn out
  float* ybuf = (float*)(aob + 3145728);      // 4096x768 fp32

  k_cvt<<<3072, 256, 0, stream>>>(x, xbf, 3145728);
  k_tr<<<dim3(36, 12), 256, 0, stream>>>(Wa, wat, 768, 2304);
  k_tr<<<dim3(12, 12), 256, 0, stream>>>(Wo, wot, 768, 768);
  k_qkv<<<dim3(36, 64), 256, 0, stream>>>(xbf, wat, ba, qbf, kbf, vtb);
  k_attn<<<dim3(64, 12), 256, 0, stream>>>(qbf, kbf, vtb, aob);
  k_out<<<dim3(12, 64), 256, 0, stream>>>(aob, wot, bo, x, ybuf);
  k_ln<<<4096, 256, 0, stream>>>(ybuf, lng, lnb, out);
}